// Round 11
// baseline (101.788 us; speedup 1.0000x reference)
//
#include <hip/hip_runtime.h>

#define SL 10
#define NI 128

typedef float f32x4 __attribute__((ext_vector_type(4)));
typedef unsigned int u32;
typedef u32 u32x4 __attribute__((ext_vector_type(4)));
typedef _Float16 h8 __attribute__((ext_vector_type(8)));

__device__ __forceinline__ f32x4 MFH(h8 a, h8 b, f32x4 c){
  return __builtin_amdgcn_mfma_f32_16x16x32_f16(a, b, c, 0, 0, 0);
}
__device__ __forceinline__ float sigf(float x){ return __fdividef(1.f, 1.f + __expf(-x)); }
__device__ __forceinline__ float tanhf2(float x){ return __fdividef(2.f, 1.f + __expf(-2.f*x)) - 1.f; }

__device__ __forceinline__ h8 to_h8(float4 a, float4 b){
  h8 r;
  r[0]=(_Float16)a.x; r[1]=(_Float16)a.y; r[2]=(_Float16)a.z; r[3]=(_Float16)a.w;
  r[4]=(_Float16)b.x; r[5]=(_Float16)b.y; r[6]=(_Float16)b.z; r[7]=(_Float16)b.w;
  return r;
}

// K-SPLIT, clean: 2 waves per 16 batch rows (wave kh owns x cols kh*64..+63)
// -> 4096 waves = 16 waves/CU demand (2x r3), testing the r9 finding that
// delivered load BW scales with per-CU wave-stream concurrency.
//   Per wave/step: 10 proj MFMAs on its K-half; partials for non-owned gate
//   tiles exchanged via PX LDS (f32x4, conflict-free [i][lane]); wave0
//   finalizes tiles 0-2 (recurrence MFMAs + bias + gates + h), wave1 tiles 3-4.
//   h shared via HB (stride 33). 2 __syncthreads per step (2-wave block).
//   A = gate-permuted weights (tile nt, A-row lr -> gate (lr&3)*20+(lr>>2)+nt*4),
//   B = x/h (col = batch row lr); C-reg ty of lane (lr,lg) = gate type ty of
//   unit nt*4+lg -> gates fully in-register. x/W 1-term f16, h 2-term f16.
// __launch_bounds__(128) ONLY — r7/r8/r10: a min-occupancy 2nd arg clamps the
// allocator below the kernel's need and spills to scratch (WRITE_SIZE 9-16x).
__global__ __launch_bounds__(128) void bilstm_kernel(
    const float* __restrict__ x,
    const float* __restrict__ Wih_f, const float* __restrict__ Whh_f,
    const float* __restrict__ bih_f, const float* __restrict__ bhh_f,
    const float* __restrict__ Wih_b,
    const float* __restrict__ bih_b, const float* __restrict__ bhh_b,
    float* __restrict__ out)
{
  __shared__ __attribute__((aligned(16))) f32x4 PXa[3][64]; // wave1 -> tiles 0-2
  __shared__ __attribute__((aligned(16))) f32x4 PXb[2][64]; // wave0 -> tiles 3-4
  __shared__ u32 HB[528];                                   // h exchange, stride 33

  const int tid  = threadIdx.x;
  const int kh   = tid >> 6;          // wave id = K-half owner
  const int lane = tid & 63;
  const int lr = lane & 15;
  const int lg = lane >> 4;
  const long b0 = (long)blockIdx.x * 16;
  const int gb = (lr&3)*20 + (lr>>2);

  for(int i=tid;i<528;i+=128) HB[i]=0;

  // W_ih_f fragments for this wave's K-half (10 frags: nt 0..4 x ks 0..1)
  h8 WIH[10];
  #pragma unroll
  for(int p=0;p<10;p++){
    const int nt=p>>1, ks=p&1;
    const float* s = Wih_f + (gb+nt*4)*NI + kh*64 + ks*32 + lg*8;
    WIH[p] = to_h8(*(const float4*)s, *(const float4*)(s+4));
  }
  // W_hh + bias for OWNED tiles only (wave0: nt 0,1,2; wave1: nt 3,4)
  const int ntown = kh ? 2 : 3;
  const int nt0   = kh ? 3 : 0;
  h8 WHH[3];
  f32x4 biasv[3];
  #pragma unroll
  for(int i=0;i<3;i++){
    const int nt = nt0 + ((i<ntown) ? i : ntown-1);   // clamp (dup) for unowned slot
    h8 r;
    #pragma unroll
    for(int j=0;j<8;j++){
      const int k = lg*8+j;
      r[j] = (_Float16)((k<20) ? Whh_f[(gb+nt*4)*20+k] : 0.f);
    }
    WHH[i]=r;
    #pragma unroll
    for(int ty=0;ty<4;ty++)
      biasv[i][ty] = bih_f[ty*20+nt*4+lg] + bhh_f[ty*20+nt*4+lg];
  }

  // x fragment source for this wave's K-half
  const float* xb = x + (b0+lr)*(long)(SL*NI) + kh*64 + lg*8;
  float4 xa0,xc0,xa1,xc1;
  xa0=*(const float4*)(xb);    xc0=*(const float4*)(xb+4);
  xa1=*(const float4*)(xb+32); xc1=*(const float4*)(xb+36);

  float cst[3]={0.f,0.f,0.f};
  h8 bx0, bx1;
  f32x4 acc[5];

  #pragma unroll
  for(int t=0;t<SL;t++){
    bx0 = to_h8(xa0,xc0); bx1 = to_h8(xa1,xc1);
    if(t+1<SL){   // prefetch next step's K-half
      const float* p = xb + (t+1)*NI;
      xa0=*(const float4*)(p);    xc0=*(const float4*)(p+4);
      xa1=*(const float4*)(p+32); xc1=*(const float4*)(p+36);
    }
    #pragma unroll
    for(int nt=0;nt<5;nt++){ f32x4 z={0.f,0.f,0.f,0.f}; acc[nt]=z; }
    // projection partials: 10 MFMAs (this K-half)
    #pragma unroll
    for(int nt=0;nt<5;nt++){
      acc[nt]=MFH(WIH[nt*2+0], bx0, acc[nt]);
      acc[nt]=MFH(WIH[nt*2+1], bx1, acc[nt]);
    }
    // exchange partials for non-owned tiles
    if(kh){ PXa[0][lane]=acc[0]; PXa[1][lane]=acc[1]; PXa[2][lane]=acc[2]; }
    else  { PXb[0][lane]=acc[3]; PXb[1][lane]=acc[4]; }
    __syncthreads();                                   // bar1: partials visible
    // h_{t-1} fragments (shared HB)
    h8 fh, fl;
    if(t>0){
      const u32* hp = HB + lr*33 + lg*8;
      u32x4 hb0=*(const u32x4*)hp, hb1=*(const u32x4*)(hp+4);
      u32x4 hhv, hlv;
      hhv[0]=(hb0[0]>>16)|(hb0[1]&0xffff0000u);
      hhv[1]=(hb0[2]>>16)|(hb0[3]&0xffff0000u);
      hhv[2]=(hb1[0]>>16)|(hb1[1]&0xffff0000u);
      hhv[3]=(hb1[2]>>16)|(hb1[3]&0xffff0000u);
      hlv[0]=(hb0[0]&0xffffu)|(hb0[1]<<16);
      hlv[1]=(hb0[2]&0xffffu)|(hb0[3]<<16);
      hlv[2]=(hb1[0]&0xffffu)|(hb1[1]<<16);
      hlv[3]=(hb1[2]&0xffffu)|(hb1[3]<<16);
      fh=__builtin_bit_cast(h8,hhv); fl=__builtin_bit_cast(h8,hlv);
    }
    // finalize owned tiles
    #pragma unroll
    for(int i=0;i<3;i++){
      if(i>=ntown) break;
      const int nt = nt0+i;
      f32x4 v = acc[nt] + (kh ? PXb[i][lane] : PXa[i][lane]) + biasv[i];
      if(t>0){
        v=MFH(WHH[i], fh, v);
        v=MFH(WHH[i], fl, v);
      }
      float ig=sigf(v[0]);
      float fg=sigf(v[1]);
      float gg=tanhf2(v[2]);
      float og=sigf(v[3]);
      cst[i]=fg*cst[i]+ig*gg;
      float hv=og*tanhf2(cst[i]);
      const int u = nt*4+lg;
      if(t==SL-1){
        out[(b0+lr)*40 + u] = hv;
      } else {
        _Float16 hh16=(_Float16)hv;
        _Float16 hl16=(_Float16)(hv-(float)hh16);
        HB[lr*33 + u] = ((u32)__builtin_bit_cast(unsigned short,hh16)<<16)
                        | (u32)__builtin_bit_cast(unsigned short,hl16);
      }
    }
    __syncthreads();                                   // bar2: h complete / PX free
  }

  // ---------------- backward direction: one step, h0=c0=0 -------------------
  // overwrite WIH with W_ih_b frags; bx0/bx1 still hold x_9
  #pragma unroll
  for(int p=0;p<10;p++){
    const int nt=p>>1, ks=p&1;
    const float* s = Wih_b + (gb+nt*4)*NI + kh*64 + ks*32 + lg*8;
    WIH[p] = to_h8(*(const float4*)s, *(const float4*)(s+4));
  }
  f32x4 a2[5];
  #pragma unroll
  for(int nt=0;nt<5;nt++){ f32x4 z={0.f,0.f,0.f,0.f}; a2[nt]=z; }
  #pragma unroll
  for(int nt=0;nt<5;nt++){
    a2[nt]=MFH(WIH[nt*2+0], bx0, a2[nt]);
    a2[nt]=MFH(WIH[nt*2+1], bx1, a2[nt]);
  }
  if(kh){ PXa[0][lane]=a2[0]; PXa[1][lane]=a2[1]; PXa[2][lane]=a2[2]; }
  else  { PXb[0][lane]=a2[3]; PXb[1][lane]=a2[4]; }
  __syncthreads();
  #pragma unroll
  for(int i=0;i<3;i++){
    if(i>=ntown) break;
    const int nt = nt0+i;
    f32x4 v = a2[nt] + (kh ? PXb[i][lane] : PXa[i][lane]);
    const int u = nt*4+lg;
    float ig=sigf(v[0]   + bih_b[u]      + bhh_b[u]);
    float gg=tanhf2(v[2] + bih_b[40+u]   + bhh_b[40+u]);
    float og=sigf(v[3]   + bih_b[60+u]   + bhh_b[60+u]);
    out[(b0+lr)*40 + 20 + u] = og*tanhf2(ig*gg);   // c = i*g (f-gate hits c0=0)
  }
}

extern "C" void kernel_launch(void* const* d_in, const int* in_sizes, int n_in,
                              void* d_out, int out_size, void* d_ws, size_t ws_size,
                              hipStream_t stream) {
  const float* x     = (const float*)d_in[0];
  const float* Wih_f = (const float*)d_in[1];
  const float* Whh_f = (const float*)d_in[2];
  const float* bih_f = (const float*)d_in[3];
  const float* bhh_f = (const float*)d_in[4];
  const float* Wih_b = (const float*)d_in[5];
  // d_in[6] = W_hh_b: provably unused (hs_b[0] has h0 = 0)
  const float* bih_b = (const float*)d_in[7];
  const float* bhh_b = (const float*)d_in[8];
  float* out = (float*)d_out;
  bilstm_kernel<<<dim3(2048), dim3(128), 0, stream>>>(
      x, Wih_f, Whh_f, bih_f, bhh_f, Wih_b, bih_b, bhh_b, out);
}